// Round 1
// baseline (772.948 us; speedup 1.0000x reference)
//
#include <hip/hip_runtime.h>
#include <hip/hip_bf16.h>

// out[b,s,e] = sum_d x[b,s,d] * kv[d,e],  kv[d,e] = sum_m keys[m,d]*vals[m,e]
// B*S = 8192, D = 1024, M = 65536. All fp32; internal compute bf16 MFMA.

typedef __attribute__((ext_vector_type(8))) __bf16 bf16x8;
typedef __attribute__((ext_vector_type(4))) __bf16 bf16x4;
typedef __attribute__((ext_vector_type(4))) float  f32x4;

#define D_DIM   1024
#define M_DIM   65536
#define ROWS    8192          // B*S
#define NCHUNK  16
#define MC      (M_DIM / NCHUNK)   // 4096
#define BT      128           // output tile edge
#define BK      64            // K step
#define LDK     72            // LDS row length in bf16 (64 + 8 pad) -> 144B stride

__device__ __forceinline__ f32x4 mfma16(bf16x8 a, bf16x8 b, f32x4 c) {
    return __builtin_amdgcn_mfma_f32_16x16x32_bf16(a, b, c, 0, 0, 0);
}

// ---------------------------------------------------------------------------
// Kernel 1: partial kv^T accumulation.  ws layout: kvw[e][d] (so that stage-2
// B-fragments read contiguous d at fixed e).
// Block: 256 threads (4 waves, 2x2 wave grid), tile 128x128, split-K chunks.
// ---------------------------------------------------------------------------
__global__ __launch_bounds__(256)
void kv_partial_kernel(const float* __restrict__ keys,
                       const float* __restrict__ vals,
                       float* __restrict__ kvw)
{
    __shared__ __bf16 Kt[BT][LDK];   // Kt[d_local][k]  (transposed from global)
    __shared__ __bf16 Vt[BT][LDK];   // Vt[e_local][k]

    const int tid  = threadIdx.x;
    const int lane = tid & 63;
    const int wave = tid >> 6;       // 0..3
    const int wr   = wave >> 1;      // wave row (d)  0..1
    const int wc   = wave & 1;       // wave col (e)  0..1

    const int tile  = blockIdx.x & 63;    // tile-fastest: chunk's 64 tiles co-resident
    const int chunk = blockIdx.x >> 6;
    const int d0 = (tile >> 3) * BT;
    const int e0 = (tile & 7) * BT;
    const size_t mbeg = (size_t)chunk * MC;

    f32x4 acc[4][4] = {};

    const int kg  = tid & 15;        // k-group: 4 consecutive m rows
    const int d4a = tid >> 4;        // 0..15 (i=0), +16 (i=1)

    for (int ms = 0; ms < MC; ms += BK) {
        // ---- stage: read fp32 rows [BK x 128], convert, write transposed ----
        #pragma unroll
        for (int i = 0; i < 2; ++i) {
            const int d4   = d4a + i * 16;   // 0..31
            const int dloc = d4 * 4;
            const size_t mrow = mbeg + ms + (size_t)kg * 4;
            f32x4 kr[4], vr[4];
            #pragma unroll
            for (int r = 0; r < 4; ++r) {
                kr[r] = *(const f32x4*)(keys + (mrow + r) * D_DIM + d0 + dloc);
                vr[r] = *(const f32x4*)(vals + (mrow + r) * D_DIM + e0 + dloc);
            }
            #pragma unroll
            for (int j = 0; j < 4; ++j) {
                bf16x4 wk, wv;
                #pragma unroll
                for (int r = 0; r < 4; ++r) {
                    wk[r] = (__bf16)kr[r][j];
                    wv[r] = (__bf16)vr[r][j];
                }
                *(bf16x4*)&Kt[dloc + j][kg * 4] = wk;
                *(bf16x4*)&Vt[dloc + j][kg * 4] = wv;
            }
        }
        __syncthreads();

        // ---- MFMA phase ----
        #pragma unroll
        for (int ks = 0; ks < BK; ks += 32) {
            bf16x8 af[4], bf[4];
            #pragma unroll
            for (int t = 0; t < 4; ++t) {
                af[t] = *(const bf16x8*)&Kt[wr * 64 + t * 16 + (lane & 15)][ks + (lane >> 4) * 8];
                bf[t] = *(const bf16x8*)&Vt[wc * 64 + t * 16 + (lane & 15)][ks + (lane >> 4) * 8];
            }
            #pragma unroll
            for (int mi = 0; mi < 4; ++mi)
                #pragma unroll
                for (int ni = 0; ni < 4; ++ni)
                    acc[mi][ni] = mfma16(af[mi], bf[ni], acc[mi][ni]);
        }
        __syncthreads();
    }

    // ---- epilogue: atomic accumulate into kvw[e][d] ----
    const int rbase = (lane >> 4) * 4;   // C/D: row = (l>>4)*4 + reg (m89)
    const int cidx  = lane & 15;         //      col = l&15
    #pragma unroll
    for (int mi = 0; mi < 4; ++mi) {
        #pragma unroll
        for (int ni = 0; ni < 4; ++ni) {
            const int e = e0 + wc * 64 + ni * 16 + cidx;
            #pragma unroll
            for (int reg = 0; reg < 4; ++reg) {
                const int d = d0 + wr * 64 + mi * 16 + rbase + reg;
                atomicAdd(kvw + (size_t)e * D_DIM + d, acc[mi][ni][reg]);
            }
        }
    }
}

// ---------------------------------------------------------------------------
// Kernel 2: out[r][e] = sum_d x[r][d] * kvw[e][d]
// ---------------------------------------------------------------------------
__global__ __launch_bounds__(256)
void out_gemm_kernel(const float* __restrict__ x,
                     const float* __restrict__ kvw,
                     float* __restrict__ out)
{
    __shared__ __bf16 Xt[BT][LDK];   // Xt[r_local][d]
    __shared__ __bf16 Wt[BT][LDK];   // Wt[e_local][d]

    const int tid  = threadIdx.x;
    const int lane = tid & 63;
    const int wave = tid >> 6;
    const int wr   = wave >> 1;
    const int wc   = wave & 1;

    const int r0 = blockIdx.x * BT;   // 64 row tiles
    const int e0 = blockIdx.y * BT;   // 8  col tiles

    f32x4 acc[4][4] = {};

    for (int ks0 = 0; ks0 < D_DIM; ks0 += BK) {
        // ---- stage (both tiles are k-contiguous in global: plain copy+cvt) ----
        #pragma unroll
        for (int i = 0; i < 8; ++i) {
            const int idx = tid + i * 256;     // 0..2047
            const int row = idx >> 4;          // 0..127
            const int col = (idx & 15) * 4;    // 0..60
            f32x4 xa = *(const f32x4*)(x   + (size_t)(r0 + row) * D_DIM + ks0 + col);
            f32x4 wa = *(const f32x4*)(kvw + (size_t)(e0 + row) * D_DIM + ks0 + col);
            bf16x4 xb, wb;
            #pragma unroll
            for (int j = 0; j < 4; ++j) {
                xb[j] = (__bf16)xa[j];
                wb[j] = (__bf16)wa[j];
            }
            *(bf16x4*)&Xt[row][col] = xb;
            *(bf16x4*)&Wt[row][col] = wb;
        }
        __syncthreads();

        // ---- MFMA phase ----
        #pragma unroll
        for (int ks = 0; ks < BK; ks += 32) {
            bf16x8 af[4], bf[4];
            #pragma unroll
            for (int t = 0; t < 4; ++t) {
                af[t] = *(const bf16x8*)&Xt[wr * 64 + t * 16 + (lane & 15)][ks + (lane >> 4) * 8];
                bf[t] = *(const bf16x8*)&Wt[wc * 64 + t * 16 + (lane & 15)][ks + (lane >> 4) * 8];
            }
            #pragma unroll
            for (int mi = 0; mi < 4; ++mi)
                #pragma unroll
                for (int ni = 0; ni < 4; ++ni)
                    acc[mi][ni] = mfma16(af[mi], bf[ni], acc[mi][ni]);
        }
        __syncthreads();
    }

    const int rbase = (lane >> 4) * 4;
    const int cidx  = lane & 15;
    #pragma unroll
    for (int mi = 0; mi < 4; ++mi) {
        #pragma unroll
        for (int ni = 0; ni < 4; ++ni) {
            const int e = e0 + wc * 64 + ni * 16 + cidx;
            #pragma unroll
            for (int reg = 0; reg < 4; ++reg) {
                const int r = r0 + wr * 64 + mi * 16 + rbase + reg;
                out[(size_t)r * D_DIM + e] = acc[mi][ni][reg];
            }
        }
    }
}

extern "C" void kernel_launch(void* const* d_in, const int* in_sizes, int n_in,
                              void* d_out, int out_size, void* d_ws, size_t ws_size,
                              hipStream_t stream) {
    const float* x    = (const float*)d_in[0];
    // d_in[1] = ver (scalar, unused)
    const float* keys = (const float*)d_in[2];
    const float* vals = (const float*)d_in[3];
    float* out = (float*)d_out;
    float* kvw = (float*)d_ws;   // kv^T, [1024][1024] fp32 = 4 MB

    hipMemsetAsync(kvw, 0, (size_t)D_DIM * D_DIM * sizeof(float), stream);
    kv_partial_kernel<<<dim3(64 * NCHUNK), dim3(256), 0, stream>>>(keys, vals, kvw);
    out_gemm_kernel<<<dim3(64, 8), dim3(256), 0, stream>>>(x, kvw, out);
}

// Round 2
// 499.514 us; speedup vs baseline: 1.5474x; 1.5474x over previous
//
#include <hip/hip_runtime.h>
#include <hip/hip_bf16.h>

// out[b,s,e] = sum_d x[b,s,d] * kv[d,e],  kv[d,e] = sum_m keys[m,d]*vals[m,e]
// B*S = 8192, D = 1024, M = 65536. fp32 in/out; internal bf16 MFMA.
//
// Pipeline (fast path, needs 272 MB ws):
//   1. convert_transpose: keys/vals fp32 [M][D] -> bf16 Kt/Vt [D][M]  (BW-bound)
//   2. kv_gemm: kvw[e][d] += sum_m Vt[e][m]*Kt[d][m]   (m97-style global_load_lds GEMM,
//      split-K 16, fp32 atomic reduce)
//   3. out_gemm: out[r][e] = sum_d x[r][d] * kvw[e][d]

typedef __attribute__((ext_vector_type(8))) __bf16 bf16x8;
typedef __attribute__((ext_vector_type(4))) __bf16 bf16x4;
typedef __attribute__((ext_vector_type(4))) float  f32x4;

#define D_DIM   1024
#define M_DIM   65536
#define ROWS    8192
#define NCHUNK  16
#define MC      (M_DIM / NCHUNK)   // 4096
#define BT      128
#define BK      64
#define LDK     72                 // padded row (bf16) for fallback + kernel2 LDS

__device__ __forceinline__ f32x4 mfma16(bf16x8 a, bf16x8 b, f32x4 c) {
    return __builtin_amdgcn_mfma_f32_16x16x32_bf16(a, b, c, 0, 0, 0);
}

__device__ __forceinline__ void gl_lds16(const void* gsrc, void* ldst) {
    __builtin_amdgcn_global_load_lds(
        (const __attribute__((address_space(1))) unsigned int*)gsrc,
        (__attribute__((address_space(3))) unsigned int*)ldst,
        16, 0, 0);
}

// ---------------------------------------------------------------------------
// Kernel A: fp32 [M][D] -> bf16 [D][M] transpose+convert.
// Tile: 128 m x 64 d per block, 256 threads. Coalesced 256B reads, 16B writes.
// ---------------------------------------------------------------------------
__global__ __launch_bounds__(256)
void convert_transpose(const float* __restrict__ keys,
                       const float* __restrict__ vals,
                       __hip_bfloat16* __restrict__ Kt,
                       __hip_bfloat16* __restrict__ Vt)
{
    __shared__ __bf16 Lt[64][136];   // [d_local][m_local], pad->272B row (16B aligned)

    const float* src = blockIdx.z ? vals : keys;
    __bf16* dst = (__bf16*)(blockIdx.z ? Vt : Kt);

    const int tid = threadIdx.x;
    const int m0 = blockIdx.x * 128;
    const int d0 = blockIdx.y * 64;

    #pragma unroll
    for (int i = 0; i < 8; ++i) {
        const int idx = tid + i * 256;       // 0..2047
        const int mr  = idx >> 4;            // 0..127
        const int c4  = (idx & 15) * 4;      // 0..60
        f32x4 v = *(const f32x4*)(src + (size_t)(m0 + mr) * D_DIM + d0 + c4);
        #pragma unroll
        for (int j = 0; j < 4; ++j)
            Lt[c4 + j][mr] = (__bf16)v[j];
    }
    __syncthreads();

    #pragma unroll
    for (int i = 0; i < 4; ++i) {
        const int idx = tid + i * 256;       // 0..1023
        const int dr  = idx >> 4;            // 0..63
        const int m8  = (idx & 15) * 8;      // 0..120
        bf16x8 w = *(const bf16x8*)&Lt[dr][m8];
        *(bf16x8*)(dst + (size_t)(d0 + dr) * M_DIM + m0 + m8) = w;
    }
}

// ---------------------------------------------------------------------------
// Kernel B: kvw[e][d] += sum_m Vt[e][m] * Kt[d][m]   (m97-style structure)
// 128x128 tile (e x d), 4 waves (2x2), BK=64, global_load_lds(16) staging,
// linear LDS [128][64], split-K over 16 chunks, fp32 atomic epilogue.
// ---------------------------------------------------------------------------
__global__ __launch_bounds__(256)
void kv_gemm(const __hip_bfloat16* __restrict__ Vt_,
             const __hip_bfloat16* __restrict__ Kt_,
             float* __restrict__ kvw)
{
    __shared__ __bf16 Va[128][64];   // e-rows
    __shared__ __bf16 Ka[128][64];   // d-rows

    const __bf16* Vt = (const __bf16*)Vt_;
    const __bf16* Kt = (const __bf16*)Kt_;

    const int tid  = threadIdx.x;
    const int lane = tid & 63;
    const int wave = tid >> 6;
    const int wr   = wave >> 1;      // e-half
    const int wc   = wave & 1;       // d-half

    const int tile  = blockIdx.x & 63;
    const int chunk = blockIdx.x >> 6;
    const int e0 = (tile >> 3) * BT;
    const int d0 = (tile & 7) * BT;
    const size_t mbeg = (size_t)chunk * MC;

    // staging geometry: per wave per round, 64 lanes x 16B = 8 rows x 64 bf16
    const int lrow = lane >> 3;          // 0..7
    const int lcol = (lane & 7) * 8;     // 0..56 (bf16 elems)

    f32x4 acc[4][4] = {};

    for (int ms = 0; ms < MC; ms += BK) {
        const size_t mcol = mbeg + ms + lcol;
        #pragma unroll
        for (int r = 0; r < 4; ++r) {
            const int row = r * 32 + wave * 8 + lrow;   // 0..127
            gl_lds16(Vt + (size_t)(e0 + row) * M_DIM + mcol, &Va[r * 32 + wave * 8][0]);
            gl_lds16(Kt + (size_t)(d0 + row) * M_DIM + mcol, &Ka[r * 32 + wave * 8][0]);
        }
        __syncthreads();   // vmcnt(0) drained by compiler before barrier

        #pragma unroll
        for (int ks = 0; ks < BK; ks += 32) {
            bf16x8 af[4], bf[4];
            #pragma unroll
            for (int t = 0; t < 4; ++t) {
                af[t] = *(const bf16x8*)&Va[wr * 64 + t * 16 + (lane & 15)][ks + (lane >> 4) * 8];
                bf[t] = *(const bf16x8*)&Ka[wc * 64 + t * 16 + (lane & 15)][ks + (lane >> 4) * 8];
            }
            #pragma unroll
            for (int mi = 0; mi < 4; ++mi)
                #pragma unroll
                for (int ni = 0; ni < 4; ++ni)
                    acc[mi][ni] = mfma16(af[mi], bf[ni], acc[mi][ni]);
        }
        __syncthreads();
    }

    // epilogue: C row-dim = A(Vt) rows = e; col-dim = B(Kt) rows = d  (m89 map)
    const int rbase = (lane >> 4) * 4;
    const int cidx  = lane & 15;
    #pragma unroll
    for (int mi = 0; mi < 4; ++mi) {
        #pragma unroll
        for (int ni = 0; ni < 4; ++ni) {
            const int d = d0 + wc * 64 + ni * 16 + cidx;
            #pragma unroll
            for (int reg = 0; reg < 4; ++reg) {
                const int e = e0 + wr * 64 + mi * 16 + rbase + reg;
                atomicAdd(kvw + (size_t)e * D_DIM + d, acc[mi][ni][reg]);
            }
        }
    }
}

// ---------------------------------------------------------------------------
// Fallback kernel 1 (R1 path): fused fp32 staging, used only if ws too small.
// ---------------------------------------------------------------------------
__global__ __launch_bounds__(256)
void kv_partial_kernel(const float* __restrict__ keys,
                       const float* __restrict__ vals,
                       float* __restrict__ kvw)
{
    __shared__ __bf16 Ktl[BT][LDK];
    __shared__ __bf16 Vtl[BT][LDK];

    const int tid  = threadIdx.x;
    const int lane = tid & 63;
    const int wave = tid >> 6;
    const int wr   = wave >> 1;
    const int wc   = wave & 1;

    const int tile  = blockIdx.x & 63;
    const int chunk = blockIdx.x >> 6;
    const int d0 = (tile >> 3) * BT;
    const int e0 = (tile & 7) * BT;
    const size_t mbeg = (size_t)chunk * MC;

    f32x4 acc[4][4] = {};
    const int kg  = tid & 15;
    const int d4a = tid >> 4;

    for (int ms = 0; ms < MC; ms += BK) {
        #pragma unroll
        for (int i = 0; i < 2; ++i) {
            const int dloc = (d4a + i * 16) * 4;
            const size_t mrow = mbeg + ms + (size_t)kg * 4;
            f32x4 kr[4], vr[4];
            #pragma unroll
            for (int r = 0; r < 4; ++r) {
                kr[r] = *(const f32x4*)(keys + (mrow + r) * D_DIM + d0 + dloc);
                vr[r] = *(const f32x4*)(vals + (mrow + r) * D_DIM + e0 + dloc);
            }
            #pragma unroll
            for (int j = 0; j < 4; ++j) {
                bf16x4 wk, wv;
                #pragma unroll
                for (int r = 0; r < 4; ++r) {
                    wk[r] = (__bf16)kr[r][j];
                    wv[r] = (__bf16)vr[r][j];
                }
                *(bf16x4*)&Ktl[dloc + j][kg * 4] = wk;
                *(bf16x4*)&Vtl[dloc + j][kg * 4] = wv;
            }
        }
        __syncthreads();

        #pragma unroll
        for (int ks = 0; ks < BK; ks += 32) {
            bf16x8 af[4], bf[4];
            #pragma unroll
            for (int t = 0; t < 4; ++t) {
                af[t] = *(const bf16x8*)&Ktl[wr * 64 + t * 16 + (lane & 15)][ks + (lane >> 4) * 8];
                bf[t] = *(const bf16x8*)&Vtl[wc * 64 + t * 16 + (lane & 15)][ks + (lane >> 4) * 8];
            }
            #pragma unroll
            for (int mi = 0; mi < 4; ++mi)
                #pragma unroll
                for (int ni = 0; ni < 4; ++ni)
                    acc[mi][ni] = mfma16(af[mi], bf[ni], acc[mi][ni]);
        }
        __syncthreads();
    }

    const int rbase = (lane >> 4) * 4;
    const int cidx  = lane & 15;
    #pragma unroll
    for (int mi = 0; mi < 4; ++mi) {
        #pragma unroll
        for (int ni = 0; ni < 4; ++ni) {
            const int e = e0 + wc * 64 + ni * 16 + cidx;
            #pragma unroll
            for (int reg = 0; reg < 4; ++reg) {
                const int d = d0 + wr * 64 + mi * 16 + rbase + reg;
                atomicAdd(kvw + (size_t)e * D_DIM + d, acc[mi][ni][reg]);
            }
        }
    }
}

// ---------------------------------------------------------------------------
// Kernel C: out[r][e] = sum_d x[r][d] * kvw[e][d]
// ---------------------------------------------------------------------------
__global__ __launch_bounds__(256)
void out_gemm_kernel(const float* __restrict__ x,
                     const float* __restrict__ kvw,
                     float* __restrict__ out)
{
    __shared__ __bf16 Xt[BT][LDK];
    __shared__ __bf16 Wt[BT][LDK];

    const int tid  = threadIdx.x;
    const int lane = tid & 63;
    const int wave = tid >> 6;
    const int wr   = wave >> 1;
    const int wc   = wave & 1;

    const int r0 = blockIdx.x * BT;
    const int e0 = blockIdx.y * BT;

    f32x4 acc[4][4] = {};

    for (int ks0 = 0; ks0 < D_DIM; ks0 += BK) {
        #pragma unroll
        for (int i = 0; i < 8; ++i) {
            const int idx = tid + i * 256;
            const int row = idx >> 4;
            const int col = (idx & 15) * 4;
            f32x4 xa = *(const f32x4*)(x   + (size_t)(r0 + row) * D_DIM + ks0 + col);
            f32x4 wa = *(const f32x4*)(kvw + (size_t)(e0 + row) * D_DIM + ks0 + col);
            bf16x4 xb, wb;
            #pragma unroll
            for (int j = 0; j < 4; ++j) {
                xb[j] = (__bf16)xa[j];
                wb[j] = (__bf16)wa[j];
            }
            *(bf16x4*)&Xt[row][col] = xb;
            *(bf16x4*)&Wt[row][col] = wb;
        }
        __syncthreads();

        #pragma unroll
        for (int ks = 0; ks < BK; ks += 32) {
            bf16x8 af[4], bf[4];
            #pragma unroll
            for (int t = 0; t < 4; ++t) {
                af[t] = *(const bf16x8*)&Xt[wr * 64 + t * 16 + (lane & 15)][ks + (lane >> 4) * 8];
                bf[t] = *(const bf16x8*)&Wt[wc * 64 + t * 16 + (lane & 15)][ks + (lane >> 4) * 8];
            }
            #pragma unroll
            for (int mi = 0; mi < 4; ++mi)
                #pragma unroll
                for (int ni = 0; ni < 4; ++ni)
                    acc[mi][ni] = mfma16(af[mi], bf[ni], acc[mi][ni]);
        }
        __syncthreads();
    }

    const int rbase = (lane >> 4) * 4;
    const int cidx  = lane & 15;
    #pragma unroll
    for (int mi = 0; mi < 4; ++mi) {
        #pragma unroll
        for (int ni = 0; ni < 4; ++ni) {
            const int e = e0 + wc * 64 + ni * 16 + cidx;
            #pragma unroll
            for (int reg = 0; reg < 4; ++reg) {
                const int r = r0 + wr * 64 + mi * 16 + rbase + reg;
                out[(size_t)r * D_DIM + e] = acc[mi][ni][reg];
            }
        }
    }
}

extern "C" void kernel_launch(void* const* d_in, const int* in_sizes, int n_in,
                              void* d_out, int out_size, void* d_ws, size_t ws_size,
                              hipStream_t stream) {
    const float* x    = (const float*)d_in[0];
    const float* keys = (const float*)d_in[2];
    const float* vals = (const float*)d_in[3];
    float* out = (float*)d_out;

    const size_t kvw_bytes = (size_t)D_DIM * D_DIM * sizeof(float);          // 4 MiB
    const size_t kt_bytes  = (size_t)D_DIM * M_DIM * sizeof(__hip_bfloat16); // 128 MiB
    const size_t need      = kvw_bytes + 2 * kt_bytes;

    float* kvw = (float*)d_ws;
    hipMemsetAsync(kvw, 0, kvw_bytes, stream);

    if (ws_size >= need) {
        __hip_bfloat16* Kt = (__hip_bfloat16*)((char*)d_ws + kvw_bytes);
        __hip_bfloat16* Vt = (__hip_bfloat16*)((char*)d_ws + kvw_bytes + kt_bytes);
        convert_transpose<<<dim3(M_DIM / 128, D_DIM / 64, 2), dim3(256), 0, stream>>>(
            keys, vals, Kt, Vt);
        kv_gemm<<<dim3(64 * NCHUNK), dim3(256), 0, stream>>>(Vt, Kt, kvw);
    } else {
        kv_partial_kernel<<<dim3(64 * NCHUNK), dim3(256), 0, stream>>>(keys, vals, kvw);
    }
    out_gemm_kernel<<<dim3(64, 8), dim3(256), 0, stream>>>(x, kvw, out);
}

// Round 3
// 472.019 us; speedup vs baseline: 1.6375x; 1.0582x over previous
//
#include <hip/hip_runtime.h>
#include <hip/hip_bf16.h>

// out[b,s,e] = sum_d x[b,s,d] * kv[d,e],  kv[d,e] = sum_m keys[m,d]*vals[m,e]
// B*S = 8192, D = 1024, M = 65536. fp32 in/out; internal bf16 MFMA.
//
// Fast path (needs 272 MB ws):
//   1. convert_transpose: fp32 [M][D] -> bf16 [D][M]      (BW-bound, ~140us)
//   2. kv_gemm: swizzled-LDS + XCD-grouped + dbuf-prefetch 2-phase GEMM,
//      split-K 16, fp32 atomic reduce into kvw[e][d]
//   3. out_gemm: out[r][e] = sum_d x[r][d] * kvw[e][d]

typedef __attribute__((ext_vector_type(8))) __bf16 bf16x8;
typedef __attribute__((ext_vector_type(4))) __bf16 bf16x4;
typedef __attribute__((ext_vector_type(4))) float  f32x4;

#define D_DIM   1024
#define M_DIM   65536
#define ROWS    8192
#define NCHUNK  16
#define MC      (M_DIM / NCHUNK)   // 4096
#define BT      128
#define BK      64
#define LDK     72

__device__ __forceinline__ f32x4 mfma16(bf16x8 a, bf16x8 b, f32x4 c) {
    return __builtin_amdgcn_mfma_f32_16x16x32_bf16(a, b, c, 0, 0, 0);
}

__device__ __forceinline__ void gl_lds16(const void* gsrc, void* ldst) {
    __builtin_amdgcn_global_load_lds(
        (const __attribute__((address_space(1))) unsigned int*)gsrc,
        (__attribute__((address_space(3))) unsigned int*)ldst,
        16, 0, 0);
}

// ---------------------------------------------------------------------------
// Kernel A: fp32 [M][D] -> bf16 [D][M] transpose+convert.
// ---------------------------------------------------------------------------
__global__ __launch_bounds__(256)
void convert_transpose(const float* __restrict__ keys,
                       const float* __restrict__ vals,
                       __hip_bfloat16* __restrict__ Kt,
                       __hip_bfloat16* __restrict__ Vt)
{
    __shared__ __bf16 Lt[64][136];

    const float* src = blockIdx.z ? vals : keys;
    __bf16* dst = (__bf16*)(blockIdx.z ? Vt : Kt);

    const int tid = threadIdx.x;
    const int m0 = blockIdx.x * 128;
    const int d0 = blockIdx.y * 64;

    #pragma unroll
    for (int i = 0; i < 8; ++i) {
        const int idx = tid + i * 256;
        const int mr  = idx >> 4;
        const int c4  = (idx & 15) * 4;
        f32x4 v = *(const f32x4*)(src + (size_t)(m0 + mr) * D_DIM + d0 + c4);
        #pragma unroll
        for (int j = 0; j < 4; ++j)
            Lt[c4 + j][mr] = (__bf16)v[j];
    }
    __syncthreads();

    #pragma unroll
    for (int i = 0; i < 4; ++i) {
        const int idx = tid + i * 256;
        const int dr  = idx >> 4;
        const int m8  = (idx & 15) * 8;
        bf16x8 w = *(const bf16x8*)&Lt[dr][m8];
        *(bf16x8*)(dst + (size_t)(d0 + dr) * M_DIM + m0 + m8) = w;
    }
}

// ---------------------------------------------------------------------------
// Kernel B: kvw[e][d] += sum_m Vt[e][m] * Kt[d][m]
// 128x128 tile, 4 waves, BK=64, double-buffered LDS with prefetch-ahead,
// XOR-swizzled LDS chunks (pre-swizzled global source, rule #21),
// XCD-grouped tile mapping (2x4 e-x-d sub-block per XCD).
// ---------------------------------------------------------------------------
__global__ __launch_bounds__(256)
void kv_gemm(const __hip_bfloat16* __restrict__ Vt_,
             const __hip_bfloat16* __restrict__ Kt_,
             float* __restrict__ kvw)
{
    __shared__ __bf16 Va[2][128][64];
    __shared__ __bf16 Ka[2][128][64];

    const __bf16* Vt = (const __bf16*)Vt_;
    const __bf16* Kt = (const __bf16*)Kt_;

    const int tid  = threadIdx.x;
    const int lane = tid & 63;
    const int wave = tid >> 6;
    const int wr   = wave >> 1;      // e-half
    const int wc   = wave & 1;       // d-half

    // --- XCD-grouped tile remap: blockIdx%8 = XCD (round-robin heuristic).
    // Each XCD gets a 2(e) x 4(d) sub-block of the 8x8 tile grid.
    const int i64   = blockIdx.x & 63;
    const int chunk = blockIdx.x >> 6;
    const int xcd   = i64 & 7;
    const int slot  = i64 >> 3;
    const int e8 = (xcd >> 1) * 2 + (slot >> 2);   // 0..7
    const int d8 = (xcd & 1) * 4 + (slot & 3);     // 0..7
    const int e0 = e8 * BT;
    const int d0 = d8 * BT;
    const size_t mbeg = (size_t)chunk * MC;

    // staging: 64 lanes x 16B = 8 rows x 8 chunks; source chunk pre-swizzled
    const int lrow = lane >> 3;                       // 0..7
    const int scol = ((lane & 7) ^ lrow) * 8;         // swizzled source chunk

    f32x4 acc[4][4] = {};

    const int l15 = lane & 15;
    const int l7  = lane & 7;
    const int hi  = lane >> 4;       // 0..3

    auto stage = [&](int buf, int ms) {
        const size_t mcol = mbeg + ms + scol;
        #pragma unroll
        for (int r = 0; r < 4; ++r) {
            const int rb = r * 32 + wave * 8;          // wave-uniform row base
            gl_lds16(Vt + (size_t)(e0 + rb + lrow) * M_DIM + mcol, &Va[buf][rb][0]);
            gl_lds16(Kt + (size_t)(d0 + rb + lrow) * M_DIM + mcol, &Ka[buf][rb][0]);
        }
    };

    stage(0, 0);
    __syncthreads();   // vmcnt(0) drained by compiler before barrier

    int cur = 0;
    for (int ms = 0; ms < MC; ms += BK) {
        if (ms + BK < MC) stage(cur ^ 1, ms + BK);   // prefetch next K-tile

        const char* vbase = (const char*)&Va[cur][0][0];
        const char* kbase = (const char*)&Ka[cur][0][0];
        #pragma unroll
        for (int ks = 0; ks < BK; ks += 32) {
            bf16x8 af[4], bf[4];
            const int ca = (ks >> 3) + hi;           // logical chunk 0..7
            const int pc = (ca ^ l7) << 4;           // physical byte slot
            #pragma unroll
            for (int t = 0; t < 4; ++t) {
                const int ra = wr * 64 + t * 16 + l15;
                const int rb = wc * 64 + t * 16 + l15;
                af[t] = *(const bf16x8*)(vbase + ra * 128 + pc);
                bf[t] = *(const bf16x8*)(kbase + rb * 128 + pc);
            }
            #pragma unroll
            for (int mi = 0; mi < 4; ++mi)
                #pragma unroll
                for (int ni = 0; ni < 4; ++ni)
                    acc[mi][ni] = mfma16(af[mi], bf[ni], acc[mi][ni]);
        }
        __syncthreads();   // prefetched buffer ready; cur buffer safe to overwrite
        cur ^= 1;
    }

    // epilogue: C row = A(Vt) rows = e; col = B(Kt) rows = d  (m89 map)
    const int rbase = (lane >> 4) * 4;
    const int cidx  = lane & 15;
    #pragma unroll
    for (int mi = 0; mi < 4; ++mi) {
        #pragma unroll
        for (int ni = 0; ni < 4; ++ni) {
            const int d = d0 + wc * 64 + ni * 16 + cidx;
            #pragma unroll
            for (int reg = 0; reg < 4; ++reg) {
                const int e = e0 + wr * 64 + mi * 16 + rbase + reg;
                atomicAdd(kvw + (size_t)e * D_DIM + d, acc[mi][ni][reg]);
            }
        }
    }
}

// ---------------------------------------------------------------------------
// Fallback (ws too small): R1 fused path, known-correct.
// ---------------------------------------------------------------------------
__global__ __launch_bounds__(256)
void kv_partial_kernel(const float* __restrict__ keys,
                       const float* __restrict__ vals,
                       float* __restrict__ kvw)
{
    __shared__ __bf16 Ktl[BT][LDK];
    __shared__ __bf16 Vtl[BT][LDK];

    const int tid  = threadIdx.x;
    const int lane = tid & 63;
    const int wave = tid >> 6;
    const int wr   = wave >> 1;
    const int wc   = wave & 1;

    const int tile  = blockIdx.x & 63;
    const int chunk = blockIdx.x >> 6;
    const int d0 = (tile >> 3) * BT;
    const int e0 = (tile & 7) * BT;
    const size_t mbeg = (size_t)chunk * MC;

    f32x4 acc[4][4] = {};
    const int kg  = tid & 15;
    const int d4a = tid >> 4;

    for (int ms = 0; ms < MC; ms += BK) {
        #pragma unroll
        for (int i = 0; i < 2; ++i) {
            const int dloc = (d4a + i * 16) * 4;
            const size_t mrow = mbeg + ms + (size_t)kg * 4;
            f32x4 kr[4], vr[4];
            #pragma unroll
            for (int r = 0; r < 4; ++r) {
                kr[r] = *(const f32x4*)(keys + (mrow + r) * D_DIM + d0 + dloc);
                vr[r] = *(const f32x4*)(vals + (mrow + r) * D_DIM + e0 + dloc);
            }
            #pragma unroll
            for (int j = 0; j < 4; ++j) {
                bf16x4 wk, wv;
                #pragma unroll
                for (int r = 0; r < 4; ++r) {
                    wk[r] = (__bf16)kr[r][j];
                    wv[r] = (__bf16)vr[r][j];
                }
                *(bf16x4*)&Ktl[dloc + j][kg * 4] = wk;
                *(bf16x4*)&Vtl[dloc + j][kg * 4] = wv;
            }
        }
        __syncthreads();

        #pragma unroll
        for (int ks = 0; ks < BK; ks += 32) {
            bf16x8 af[4], bf[4];
            #pragma unroll
            for (int t = 0; t < 4; ++t) {
                af[t] = *(const bf16x8*)&Ktl[wr * 64 + t * 16 + (lane & 15)][ks + (lane >> 4) * 8];
                bf[t] = *(const bf16x8*)&Vtl[wc * 64 + t * 16 + (lane & 15)][ks + (lane >> 4) * 8];
            }
            #pragma unroll
            for (int mi = 0; mi < 4; ++mi)
                #pragma unroll
                for (int ni = 0; ni < 4; ++ni)
                    acc[mi][ni] = mfma16(af[mi], bf[ni], acc[mi][ni]);
        }
        __syncthreads();
    }

    const int rbase = (lane >> 4) * 4;
    const int cidx  = lane & 15;
    #pragma unroll
    for (int mi = 0; mi < 4; ++mi) {
        #pragma unroll
        for (int ni = 0; ni < 4; ++ni) {
            const int e = e0 + wc * 64 + ni * 16 + cidx;
            #pragma unroll
            for (int reg = 0; reg < 4; ++reg) {
                const int d = d0 + wr * 64 + mi * 16 + rbase + reg;
                atomicAdd(kvw + (size_t)e * D_DIM + d, acc[mi][ni][reg]);
            }
        }
    }
}

// ---------------------------------------------------------------------------
// Kernel C: out[r][e] = sum_d x[r][d] * kvw[e][d]
// ---------------------------------------------------------------------------
__global__ __launch_bounds__(256)
void out_gemm_kernel(const float* __restrict__ x,
                     const float* __restrict__ kvw,
                     float* __restrict__ out)
{
    __shared__ __bf16 Xt[BT][LDK];
    __shared__ __bf16 Wt[BT][LDK];

    const int tid  = threadIdx.x;
    const int lane = tid & 63;
    const int wave = tid >> 6;
    const int wr   = wave >> 1;
    const int wc   = wave & 1;

    const int r0 = blockIdx.x * BT;
    const int e0 = blockIdx.y * BT;

    f32x4 acc[4][4] = {};

    for (int ks0 = 0; ks0 < D_DIM; ks0 += BK) {
        #pragma unroll
        for (int i = 0; i < 8; ++i) {
            const int idx = tid + i * 256;
            const int row = idx >> 4;
            const int col = (idx & 15) * 4;
            f32x4 xa = *(const f32x4*)(x   + (size_t)(r0 + row) * D_DIM + ks0 + col);
            f32x4 wa = *(const f32x4*)(kvw + (size_t)(e0 + row) * D_DIM + ks0 + col);
            bf16x4 xb, wb;
            #pragma unroll
            for (int j = 0; j < 4; ++j) {
                xb[j] = (__bf16)xa[j];
                wb[j] = (__bf16)wa[j];
            }
            *(bf16x4*)&Xt[row][col] = xb;
            *(bf16x4*)&Wt[row][col] = wb;
        }
        __syncthreads();

        #pragma unroll
        for (int ks = 0; ks < BK; ks += 32) {
            bf16x8 af[4], bf[4];
            #pragma unroll
            for (int t = 0; t < 4; ++t) {
                af[t] = *(const bf16x8*)&Xt[wr * 64 + t * 16 + (lane & 15)][ks + (lane >> 4) * 8];
                bf[t] = *(const bf16x8*)&Wt[wc * 64 + t * 16 + (lane & 15)][ks + (lane >> 4) * 8];
            }
            #pragma unroll
            for (int mi = 0; mi < 4; ++mi)
                #pragma unroll
                for (int ni = 0; ni < 4; ++ni)
                    acc[mi][ni] = mfma16(af[mi], bf[ni], acc[mi][ni]);
        }
        __syncthreads();
    }

    const int rbase = (lane >> 4) * 4;
    const int cidx  = lane & 15;
    #pragma unroll
    for (int mi = 0; mi < 4; ++mi) {
        #pragma unroll
        for (int ni = 0; ni < 4; ++ni) {
            const int e = e0 + wc * 64 + ni * 16 + cidx;
            #pragma unroll
            for (int reg = 0; reg < 4; ++reg) {
                const int r = r0 + wr * 64 + mi * 16 + rbase + reg;
                out[(size_t)r * D_DIM + e] = acc[mi][ni][reg];
            }
        }
    }
}

extern "C" void kernel_launch(void* const* d_in, const int* in_sizes, int n_in,
                              void* d_out, int out_size, void* d_ws, size_t ws_size,
                              hipStream_t stream) {
    const float* x    = (const float*)d_in[0];
    const float* keys = (const float*)d_in[2];
    const float* vals = (const float*)d_in[3];
    float* out = (float*)d_out;

    const size_t kvw_bytes = (size_t)D_DIM * D_DIM * sizeof(float);
    const size_t kt_bytes  = (size_t)D_DIM * M_DIM * sizeof(__hip_bfloat16);
    const size_t need      = kvw_bytes + 2 * kt_bytes;

    float* kvw = (float*)d_ws;
    hipMemsetAsync(kvw, 0, kvw_bytes, stream);

    if (ws_size >= need) {
        __hip_bfloat16* Kt = (__hip_bfloat16*)((char*)d_ws + kvw_bytes);
        __hip_bfloat16* Vt = (__hip_bfloat16*)((char*)d_ws + kvw_bytes + kt_bytes);
        convert_transpose<<<dim3(M_DIM / 128, D_DIM / 64, 2), dim3(256), 0, stream>>>(
            keys, vals, Kt, Vt);
        kv_gemm<<<dim3(64 * NCHUNK), dim3(256), 0, stream>>>(Vt, Kt, kvw);
    } else {
        kv_partial_kernel<<<dim3(64 * NCHUNK), dim3(256), 0, stream>>>(keys, vals, kvw);
    }
    out_gemm_kernel<<<dim3(64, 8), dim3(256), 0, stream>>>(x, kvw, out);
}

// Round 4
// 425.886 us; speedup vs baseline: 1.8149x; 1.1083x over previous
//
#include <hip/hip_runtime.h>
#include <hip/hip_bf16.h>

// out[b,s,e] = sum_d x[b,s,d] * kv[d,e],  kv[d,e] = sum_m keys[m,d]*vals[m,e]
// B*S = 8192, D = 1024, M = 65536. fp32 in/out; internal bf16 MFMA.
//
// Fast path (needs 260 MB ws):
//   1. convert_tile: fp32 [M][D] -> bf16 tiled "LDS-image" layout:
//        T[d_tile(8)][m_step(1024)][128 rows][64 m] with XOR swizzle baked in:
//        element (row r, m-chunk cl, j) at byte r*128 + (cl^(r&7))*16 + j*2.
//      kv_gemm staging then reads CONTIGUOUS 16KB tiles (streaming HBM).
//   2. kv_gemm: m97 single-buffer 2-barrier structure, identity gl_lds,
//      swizzled ds_read (conflicts=0, verified R3), XCD-grouped tiles,
//      split-K 16, fp32 atomic reduce into kvw[e][d].
//   3. out_gemm: out[r][e] = sum_d x[r][d] * kvw[e][d]

typedef __attribute__((ext_vector_type(8))) __bf16 bf16x8;
typedef __attribute__((ext_vector_type(4))) __bf16 bf16x4;
typedef __attribute__((ext_vector_type(4))) float  f32x4;

#define D_DIM   1024
#define M_DIM   65536
#define ROWS    8192
#define NCHUNK  16
#define MC      (M_DIM / NCHUNK)   // 4096 m per chunk = 64 K-steps
#define BT      128
#define BK      64
#define LDK     72
#define TILE_BYTES 16384           // one [128][64] bf16 tile

__device__ __forceinline__ f32x4 mfma16(bf16x8 a, bf16x8 b, f32x4 c) {
    return __builtin_amdgcn_mfma_f32_16x16x32_bf16(a, b, c, 0, 0, 0);
}

__device__ __forceinline__ void gl_lds16(const void* gsrc, void* ldst) {
    __builtin_amdgcn_global_load_lds(
        (const __attribute__((address_space(1))) unsigned int*)gsrc,
        (__attribute__((address_space(3))) unsigned int*)ldst,
        16, 0, 0);
}

// ---------------------------------------------------------------------------
// Kernel A: fp32 [M][D] -> swizzled bf16 tiles.
// Block handles one output tile: 64 m x 128 d  (32KB in, 16KB out).
// grid = (1024 m-steps, 8 d-tiles, 2 {keys,vals})
// ---------------------------------------------------------------------------
__global__ __launch_bounds__(256)
void convert_tile(const float* __restrict__ keys,
                  const float* __restrict__ vals,
                  __hip_bfloat16* __restrict__ KtT,
                  __hip_bfloat16* __restrict__ VtT)
{
    __shared__ __bf16 Lt[128][72];   // [d_local][m_local], 144B row (16B aligned)

    const float* src = blockIdx.z ? vals : keys;
    char* dstb = (char*)(blockIdx.z ? VtT : KtT);

    const int tid = threadIdx.x;
    const int s  = blockIdx.x;        // m-step
    const int t  = blockIdx.y;        // d-tile
    const int m0 = s * 64;
    const int d0 = t * 128;

    // read 64 m-rows x 512B, transpose into Lt[d][m]
    #pragma unroll
    for (int i = 0; i < 8; ++i) {
        const int idx = tid + i * 256;       // 0..2047
        const int mr  = idx >> 5;            // 0..63
        const int dc  = (idx & 31) * 4;      // 0..124
        f32x4 v = *(const f32x4*)(src + (size_t)(m0 + mr) * D_DIM + d0 + dc);
        #pragma unroll
        for (int j = 0; j < 4; ++j)
            Lt[dc + j][mr] = (__bf16)v[j];
    }
    __syncthreads();

    // write 16KB tile, swizzle baked in: physical chunk c of row dl holds
    // logical chunk cl = c ^ (dl&7)
    char* dst_tile = dstb + ((size_t)t * 1024 + s) * TILE_BYTES;
    #pragma unroll
    for (int r = 0; r < 4; ++r) {
        const int o  = r * 4096 + tid * 16;  // byte offset in tile
        const int dl = o >> 7;               // 0..127
        const int c  = (o >> 4) & 7;         // physical chunk
        const int cl = c ^ (dl & 7);         // logical chunk
        bf16x8 w = *(const bf16x8*)&Lt[dl][cl * 8];
        *(bf16x8*)(dst_tile + o) = w;
    }
}

// ---------------------------------------------------------------------------
// Kernel B: kvw[e][d] += sum_m V[e][m] * K[d][m], operands in tiled layout.
// 128x128 tile, 4 waves, BK=64, single-buffer 32KB LDS (m97 2-barrier),
// identity gl_lds from contiguous tiles, swizzled ds_read.
// ---------------------------------------------------------------------------
__global__ __launch_bounds__(256)
void kv_gemm(const __hip_bfloat16* __restrict__ VtT,
             const __hip_bfloat16* __restrict__ KtT,
             float* __restrict__ kvw)
{
    __shared__ __bf16 Va[128][64];   // e-rows, physical-chunk (swizzled) layout
    __shared__ __bf16 Ka[128][64];   // d-rows

    const int tid  = threadIdx.x;
    const int lane = tid & 63;
    const int wave = tid >> 6;
    const int wr   = wave >> 1;      // e-half
    const int wc   = wave & 1;       // d-half

    // XCD-grouped tile remap: each XCD gets a 2(e) x 4(d) sub-block
    const int i64   = blockIdx.x & 63;
    const int chunk = blockIdx.x >> 6;
    const int xcd   = i64 & 7;
    const int slot  = i64 >> 3;
    const int e8 = (xcd >> 1) * 2 + (slot >> 2);
    const int d8 = (xcd & 1) * 4 + (slot & 3);

    const char* srcV = (const char*)VtT
        + ((size_t)e8 * 1024 + (size_t)chunk * 64) * TILE_BYTES
        + wave * 4096 + lane * 16;
    const char* srcK = (const char*)KtT
        + ((size_t)d8 * 1024 + (size_t)chunk * 64) * TILE_BYTES
        + wave * 4096 + lane * 16;
    char* dstV = (char*)&Va[0][0] + wave * 4096;   // lane offset implicit
    char* dstK = (char*)&Ka[0][0] + wave * 4096;

    f32x4 acc[4][4] = {};

    const int l15 = lane & 15;
    const int l7  = lane & 7;        // = row&7 of the fragment rows read below
    const int hi  = lane >> 4;       // 0..3

    for (int it = 0; it < 64; ++it) {
        #pragma unroll
        for (int i = 0; i < 4; ++i) {
            gl_lds16(srcV + i * 1024, dstV + i * 1024);
            gl_lds16(srcK + i * 1024, dstK + i * 1024);
        }
        __syncthreads();   // compiler drains vmcnt(0) before barrier

        const char* vbase = (const char*)&Va[0][0];
        const char* kbase = (const char*)&Ka[0][0];
        #pragma unroll
        for (int ks = 0; ks < BK; ks += 32) {
            bf16x8 af[4], bf[4];
            const int ca = (ks >> 3) + hi;           // logical chunk
            const int pc = (ca ^ l7) << 4;           // physical byte slot
            #pragma unroll
            for (int tt = 0; tt < 4; ++tt) {
                const int ra = wr * 64 + tt * 16 + l15;
                const int rb = wc * 64 + tt * 16 + l15;
                af[tt] = *(const bf16x8*)(vbase + ra * 128 + pc);
                bf[tt] = *(const bf16x8*)(kbase + rb * 128 + pc);
            }
            #pragma unroll
            for (int mi = 0; mi < 4; ++mi)
                #pragma unroll
                for (int ni = 0; ni < 4; ++ni)
                    acc[mi][ni] = mfma16(af[mi], bf[ni], acc[mi][ni]);
        }
        __syncthreads();   // protect next stage from current reads

        srcV += TILE_BYTES;
        srcK += TILE_BYTES;
    }

    // epilogue: C row = V rows = e; col = K rows = d  (m89 map)
    const int rbase = (lane >> 4) * 4;
    const int cidx  = lane & 15;
    #pragma unroll
    for (int mi = 0; mi < 4; ++mi) {
        #pragma unroll
        for (int ni = 0; ni < 4; ++ni) {
            const int d = d8 * BT + wc * 64 + ni * 16 + cidx;
            #pragma unroll
            for (int reg = 0; reg < 4; ++reg) {
                const int e = e8 * BT + wr * 64 + mi * 16 + rbase + reg;
                atomicAdd(kvw + (size_t)e * D_DIM + d, acc[mi][ni][reg]);
            }
        }
    }
}

// ---------------------------------------------------------------------------
// Fallback (ws too small): R1 fused path, known-correct.
// ---------------------------------------------------------------------------
__global__ __launch_bounds__(256)
void kv_partial_kernel(const float* __restrict__ keys,
                       const float* __restrict__ vals,
                       float* __restrict__ kvw)
{
    __shared__ __bf16 Ktl[BT][LDK];
    __shared__ __bf16 Vtl[BT][LDK];

    const int tid  = threadIdx.x;
    const int lane = tid & 63;
    const int wave = tid >> 6;
    const int wr   = wave >> 1;
    const int wc   = wave & 1;

    const int tile  = blockIdx.x & 63;
    const int chunk = blockIdx.x >> 6;
    const int d0 = (tile >> 3) * BT;
    const int e0 = (tile & 7) * BT;
    const size_t mbeg = (size_t)chunk * MC;

    f32x4 acc[4][4] = {};
    const int kg  = tid & 15;
    const int d4a = tid >> 4;

    for (int ms = 0; ms < MC; ms += BK) {
        #pragma unroll
        for (int i = 0; i < 2; ++i) {
            const int dloc = (d4a + i * 16) * 4;
            const size_t mrow = mbeg + ms + (size_t)kg * 4;
            f32x4 kr[4], vr[4];
            #pragma unroll
            for (int r = 0; r < 4; ++r) {
                kr[r] = *(const f32x4*)(keys + (mrow + r) * D_DIM + d0 + dloc);
                vr[r] = *(const f32x4*)(vals + (mrow + r) * D_DIM + e0 + dloc);
            }
            #pragma unroll
            for (int j = 0; j < 4; ++j) {
                bf16x4 wk, wv;
                #pragma unroll
                for (int r = 0; r < 4; ++r) {
                    wk[r] = (__bf16)kr[r][j];
                    wv[r] = (__bf16)vr[r][j];
                }
                *(bf16x4*)&Ktl[dloc + j][kg * 4] = wk;
                *(bf16x4*)&Vtl[dloc + j][kg * 4] = wv;
            }
        }
        __syncthreads();

        #pragma unroll
        for (int ks = 0; ks < BK; ks += 32) {
            bf16x8 af[4], bf[4];
            #pragma unroll
            for (int t = 0; t < 4; ++t) {
                af[t] = *(const bf16x8*)&Ktl[wr * 64 + t * 16 + (lane & 15)][ks + (lane >> 4) * 8];
                bf[t] = *(const bf16x8*)&Vtl[wc * 64 + t * 16 + (lane & 15)][ks + (lane >> 4) * 8];
            }
            #pragma unroll
            for (int mi = 0; mi < 4; ++mi)
                #pragma unroll
                for (int ni = 0; ni < 4; ++ni)
                    acc[mi][ni] = mfma16(af[mi], bf[ni], acc[mi][ni]);
        }
        __syncthreads();
    }

    const int rbase = (lane >> 4) * 4;
    const int cidx  = lane & 15;
    #pragma unroll
    for (int mi = 0; mi < 4; ++mi) {
        #pragma unroll
        for (int ni = 0; ni < 4; ++ni) {
            const int e = e0 + wc * 64 + ni * 16 + cidx;
            #pragma unroll
            for (int reg = 0; reg < 4; ++reg) {
                const int d = d0 + wr * 64 + mi * 16 + rbase + reg;
                atomicAdd(kvw + (size_t)e * D_DIM + d, acc[mi][ni][reg]);
            }
        }
    }
}

// ---------------------------------------------------------------------------
// Kernel C: out[r][e] = sum_d x[r][d] * kvw[e][d]
// ---------------------------------------------------------------------------
__global__ __launch_bounds__(256)
void out_gemm_kernel(const float* __restrict__ x,
                     const float* __restrict__ kvw,
                     float* __restrict__ out)
{
    __shared__ __bf16 Xt[BT][LDK];
    __shared__ __bf16 Wt[BT][LDK];

    const int tid  = threadIdx.x;
    const int lane = tid & 63;
    const int wave = tid >> 6;
    const int wr   = wave >> 1;
    const int wc   = wave & 1;

    const int r0 = blockIdx.x * BT;
    const int e0 = blockIdx.y * BT;

    f32x4 acc[4][4] = {};

    for (int ks0 = 0; ks0 < D_DIM; ks0 += BK) {
        #pragma unroll
        for (int i = 0; i < 8; ++i) {
            const int idx = tid + i * 256;
            const int row = idx >> 4;
            const int col = (idx & 15) * 4;
            f32x4 xa = *(const f32x4*)(x   + (size_t)(r0 + row) * D_DIM + ks0 + col);
            f32x4 wa = *(const f32x4*)(kvw + (size_t)(e0 + row) * D_DIM + ks0 + col);
            bf16x4 xb, wb;
            #pragma unroll
            for (int j = 0; j < 4; ++j) {
                xb[j] = (__bf16)xa[j];
                wb[j] = (__bf16)wa[j];
            }
            *(bf16x4*)&Xt[row][col] = xb;
            *(bf16x4*)&Wt[row][col] = wb;
        }
        __syncthreads();

        #pragma unroll
        for (int ks = 0; ks < BK; ks += 32) {
            bf16x8 af[4], bf[4];
            #pragma unroll
            for (int t = 0; t < 4; ++t) {
                af[t] = *(const bf16x8*)&Xt[wr * 64 + t * 16 + (lane & 15)][ks + (lane >> 4) * 8];
                bf[t] = *(const bf16x8*)&Wt[wc * 64 + t * 16 + (lane & 15)][ks + (lane >> 4) * 8];
            }
            #pragma unroll
            for (int mi = 0; mi < 4; ++mi)
                #pragma unroll
                for (int ni = 0; ni < 4; ++ni)
                    acc[mi][ni] = mfma16(af[mi], bf[ni], acc[mi][ni]);
        }
        __syncthreads();
    }

    const int rbase = (lane >> 4) * 4;
    const int cidx  = lane & 15;
    #pragma unroll
    for (int mi = 0; mi < 4; ++mi) {
        #pragma unroll
        for (int ni = 0; ni < 4; ++ni) {
            const int e = e0 + wc * 64 + ni * 16 + cidx;
            #pragma unroll
            for (int reg = 0; reg < 4; ++reg) {
                const int r = r0 + wr * 64 + mi * 16 + rbase + reg;
                out[(size_t)r * D_DIM + e] = acc[mi][ni][reg];
            }
        }
    }
}

extern "C" void kernel_launch(void* const* d_in, const int* in_sizes, int n_in,
                              void* d_out, int out_size, void* d_ws, size_t ws_size,
                              hipStream_t stream) {
    const float* x    = (const float*)d_in[0];
    const float* keys = (const float*)d_in[2];
    const float* vals = (const float*)d_in[3];
    float* out = (float*)d_out;

    const size_t kvw_bytes = (size_t)D_DIM * D_DIM * sizeof(float);          // 4 MiB
    const size_t kt_bytes  = (size_t)D_DIM * M_DIM * sizeof(__hip_bfloat16); // 128 MiB
    const size_t need      = kvw_bytes + 2 * kt_bytes;

    float* kvw = (float*)d_ws;
    hipMemsetAsync(kvw, 0, kvw_bytes, stream);

    if (ws_size >= need) {
        __hip_bfloat16* KtT = (__hip_bfloat16*)((char*)d_ws + kvw_bytes);
        __hip_bfloat16* VtT = (__hip_bfloat16*)((char*)d_ws + kvw_bytes + kt_bytes);
        convert_tile<<<dim3(M_DIM / 64, D_DIM / 128, 2), dim3(256), 0, stream>>>(
            keys, vals, KtT, VtT);
        kv_gemm<<<dim3(64 * NCHUNK), dim3(256), 0, stream>>>(VtT, KtT, kvw);
    } else {
        kv_partial_kernel<<<dim3(64 * NCHUNK), dim3(256), 0, stream>>>(keys, vals, kvw);
    }
    out_gemm_kernel<<<dim3(64, 8), dim3(256), 0, stream>>>(x, kvw, out);
}